// Round 1
// baseline (937.019 us; speedup 1.0000x reference)
//
#include <hip/hip_runtime.h>

// Depthwise 9x9 cross-correlation, single shared kernel, stride 1, pad 4.
// X: (32,64,256,256) fp32  -> 2048 independent 256x256 planes
// K: (1,1,9,9) fp32
// out: (32,64,256,256) fp32
//
// Block: 256 threads, one 64x64 output tile (16 tiles per plane).
// LDS: 72x72 input tile (halo 4 each side). Each thread: 4x4 outputs,
// 12 LDS row-reads of 12 floats (3x float4), 1296 FMAs fully unrolled.

#define CONV_H 256
#define CONV_W 256
#define TILE 64
#define HALO 4
#define LDS_DIM 72  // TILE + 2*HALO
#define NPLANES 2048

__global__ __launch_bounds__(256)
void conv9x9_kernel(const float* __restrict__ X,
                    const float* __restrict__ K,
                    float* __restrict__ out)
{
    __shared__ float lds[LDS_DIM * LDS_DIM];

    const int tid   = threadIdx.x;
    const int bid   = blockIdx.x;
    const int plane = bid >> 4;          // 16 tiles per plane
    const int tile  = bid & 15;
    const int tile_y = (tile >> 2) << 6; // 0,64,128,192
    const int tile_x = (tile & 3) << 6;

    const float* Xp = X + (size_t)plane * (CONV_H * CONV_W);

    // ---- load the 81 wave-uniform weights (compiler should scalarize) ----
    float kw[81];
#pragma unroll
    for (int i = 0; i < 81; ++i) kw[i] = K[i];

    // ---- stage 72x72 input tile (with halo) into LDS ----
    // 72 rows x 18 float4 = 1296 float4 slots.
    // halo == 4 == float4 width, and tile_x % 64 == 0, so every slot is
    // either fully in-range or fully out-of-range (zero fill).
    for (int s = tid; s < LDS_DIM * (LDS_DIM / 4); s += 256) {
        int row  = s / (LDS_DIM / 4);
        int colv = s - row * (LDS_DIM / 4);
        int gy = tile_y - HALO + row;
        int gx = tile_x - HALO + colv * 4;
        float4 v = make_float4(0.f, 0.f, 0.f, 0.f);
        if ((unsigned)gy < CONV_H && (unsigned)gx < CONV_W) {
            v = *reinterpret_cast<const float4*>(Xp + gy * CONV_W + gx);
        }
        *reinterpret_cast<float4*>(&lds[row * LDS_DIM + colv * 4]) = v;
    }
    __syncthreads();

    // ---- compute 4x4 outputs per thread ----
    const int tx  = tid & 15;
    const int ty  = tid >> 4;
    const int ox0 = tx << 2;   // output col within tile
    const int oy0 = ty << 2;   // output row within tile

    float acc[4][4] = {{0.f}};

#pragma unroll
    for (int r = 0; r < 12; ++r) {
        float rowv[12];
        const float* lp = &lds[(oy0 + r) * LDS_DIM + ox0];
        *reinterpret_cast<float4*>(&rowv[0]) = *reinterpret_cast<const float4*>(lp);
        *reinterpret_cast<float4*>(&rowv[4]) = *reinterpret_cast<const float4*>(lp + 4);
        *reinterpret_cast<float4*>(&rowv[8]) = *reinterpret_cast<const float4*>(lp + 8);
#pragma unroll
        for (int i = 0; i < 4; ++i) {
            const int u = r - i;             // kernel row; constant-folded
            if (u >= 0 && u < 9) {
#pragma unroll
                for (int v = 0; v < 9; ++v) {
                    const float w = kw[u * 9 + v];
#pragma unroll
                    for (int j = 0; j < 4; ++j)
                        acc[i][j] = fmaf(rowv[v + j], w, acc[i][j]);
                }
            }
        }
    }

    // ---- store 4x4 outputs (float4 rows, 16B aligned) ----
    float* Op = out + (size_t)plane * (CONV_H * CONV_W)
                    + (size_t)(tile_y + oy0) * CONV_W + (tile_x + ox0);
#pragma unroll
    for (int i = 0; i < 4; ++i) {
        float4 v = make_float4(acc[i][0], acc[i][1], acc[i][2], acc[i][3]);
        *reinterpret_cast<float4*>(Op + i * CONV_W) = v;
    }
}

extern "C" void kernel_launch(void* const* d_in, const int* in_sizes, int n_in,
                              void* d_out, int out_size, void* d_ws, size_t ws_size,
                              hipStream_t stream) {
    const float* X = (const float*)d_in[0];
    const float* K = (const float*)d_in[1];
    float* out = (float*)d_out;

    const int nblocks = NPLANES * 16;  // 32768 blocks of 256 threads
    conv9x9_kernel<<<nblocks, 256, 0, stream>>>(X, K, out);
}